// Round 1
// 1025.662 us; speedup vs baseline: 1.0350x; 1.0350x over previous
//
#include <hip/hip_runtime.h>
#include <hip/hip_bf16.h>
#include <stdint.h>

// Problem dims
#define B_ 4
#define T_ 128
#define H_ 1024
#define N_ 300
#define V_ 50265
#define E_ 4800
#define R_ (B_*T_)   // 512 rows
#define GK 2048

// ---- workspace layout (floats) ----
#define U_OFF     0                       // u_h[1024],u_s[1024],u_x[1024], c at [3072]
#define PS_OFF    3080
#define GG_OFF    3592
#define MG_OFF    4104
#define Z_OFF     4616
#define M_OFF     (Z_OFF + R_*N_)
#define CP_OFF    (M_OFF + R_*N_)
#define GRAPH_OFF (CP_OFF + R_*N_)
#define COV_OFF   (GRAPH_OFF + B_*N_*N_)
#define FLAG_OFF  (COV_OFF + B_*N_)       // int flag: 1=bf16 inputs, 0=f32

// out offsets (elements): total_pro, coverage, pro_switch
#define OUT_COV ((size_t)R_*V_)
#define OUT_PS  (OUT_COV + (size_t)B_*N_)

typedef unsigned short ushort_t;
typedef __bf16 bf16x8 __attribute__((ext_vector_type(8)));
typedef float  f32x4  __attribute__((ext_vector_type(4)));
typedef unsigned short ushort8v __attribute__((ext_vector_type(8)));
typedef unsigned short ushort4v __attribute__((ext_vector_type(4)));
typedef float f32x4v __attribute__((ext_vector_type(4)));

__device__ __forceinline__ ushort_t f2bf(float f) {
    unsigned u = __float_as_uint(f);
    unsigned r = (u + 0x7fffu + ((u >> 16) & 1u)) >> 16;   // RNE
    return (ushort_t)r;
}
template<bool BF> __device__ __forceinline__ float ldv(const void* p, size_t i) {
    if constexpr (BF) {
        unsigned u = ((unsigned)((const ushort_t*)p)[i]) << 16;
        return __uint_as_float(u);
    } else {
        return ((const float*)p)[i];
    }
}
template<bool BF> __device__ __forceinline__ void stv(void* p, size_t i, float v) {
    if constexpr (BF) ((ushort_t*)p)[i] = f2bf(v);
    else              ((float*)p)[i] = v;
}
__device__ __forceinline__ float sigm(float x) { return 1.0f / (1.0f + expf(-x)); }

// ---------------------------------------------------------------------------
// Probe: classify input dtype. bf16 N(0,1): every ushort has exponent~[100,140]
// (cnt~256). f32 N(0,1): only hi half-words do (cnt~148). Threshold 200.
// ---------------------------------------------------------------------------
__global__ void k_probe(const ushort_t* __restrict__ x, int* __restrict__ flag)
{
    if (threadIdx.x == 0 && blockIdx.x == 0) {
        int cnt = 0;
        for (int i = 0; i < 256; ++i) {
            const int e = (x[i] >> 7) & 0xff;
            cnt += (e >= 100 && e <= 140) ? 1 : 0;
        }
        *flag = (cnt > 200) ? 1 : 0;
    }
}

// ---------------------------------------------------------------------------
// K_u: u rows 0..3071 = (Wh|Ws|Wx) @ Wps; row 3072 -> c = bx.Wps + bps
// ---------------------------------------------------------------------------
template<bool BF>
__global__ __launch_bounds__(256)
void k_u(const int* __restrict__ flag,
         const void* __restrict__ Wh, const void* __restrict__ Wsm,
         const void* __restrict__ Wx, const void* __restrict__ bx,
         const void* __restrict__ Wps, const void* __restrict__ bps,
         float* __restrict__ u)
{
    if (*flag != (BF ? 1 : 0)) return;
    const int t = threadIdx.x, w = t >> 6, l = t & 63;
    const int row = blockIdx.x * 4 + w;
    if (row > 3072) return;
    float s = 0.f;
    if (row < 3072) {
        const void* W = (row < 1024) ? Wh : (row < 2048) ? Wsm : Wx;
        const size_t k = (size_t)(row & 1023);
        for (int h = l; h < H_; h += 64)
            s += ldv<BF>(W, k*H_ + h) * ldv<BF>(Wps, h);
    } else {
        for (int h = l; h < H_; h += 64)
            s += ldv<BF>(bx, h) * ldv<BF>(Wps, h);
    }
    for (int o = 32; o; o >>= 1) s += __shfl_down(s, o);
    if (l == 0) {
        if (row < 3072) u[row] = s;
        else            u[3072] = s + ldv<BF>(bps, 0);
    }
}

// ---------------------------------------------------------------------------
// K_rows: ps/gg/mg per row; writes pro_switch output
// ---------------------------------------------------------------------------
template<bool BF>
__global__ __launch_bounds__(256)
void k_rows(const int* __restrict__ flag,
            const void* __restrict__ hs, const void* __restrict__ qt,
            const void* __restrict__ te, const float* __restrict__ u,
            const void* __restrict__ Wgg, const void* __restrict__ bgg,
            const void* __restrict__ Wmg, const void* __restrict__ bmg,
            float* __restrict__ ps, float* __restrict__ gg, float* __restrict__ mg,
            void* __restrict__ out_ps)
{
    if (*flag != (BF ? 1 : 0)) return;
    const int r = blockIdx.x, t = threadIdx.x;
    const float* uh = u; const float* us = u + 1024; const float* ux = u + 2048;
    float s1 = 0.f, s2 = 0.f, s3 = 0.f;
    for (int k = t; k < H_; k += 256) {
        const float a = ldv<BF>(hs, (size_t)r*H_ + k);
        const float b = ldv<BF>(qt, (size_t)r*H_ + k);
        const float c = ldv<BF>(te, (size_t)r*H_ + k);
        s1 += a*uh[k] + b*us[k] + c*ux[k];
        s2 += a*ldv<BF>(Wgg, k) + b*ldv<BF>(Wgg, H_ + k);
        s3 += a*ldv<BF>(Wmg, k) + b*ldv<BF>(Wmg, H_ + k);
    }
    for (int o = 32; o; o >>= 1) {
        s1 += __shfl_down(s1, o); s2 += __shfl_down(s2, o); s3 += __shfl_down(s3, o);
    }
    __shared__ float red[3][4];
    const int w = t >> 6, l = t & 63;
    if (l == 0) { red[0][w] = s1; red[1][w] = s2; red[2][w] = s3; }
    __syncthreads();
    if (t == 0) {
        const float S1 = red[0][0]+red[0][1]+red[0][2]+red[0][3] + u[3072];
        const float S2 = red[1][0]+red[1][1]+red[1][2]+red[1][3] + ldv<BF>(bgg, 0);
        const float S3 = red[2][0]+red[2][1]+red[2][2]+red[2][3] + ldv<BF>(bmg, 0);
        const float p = sigm(S1);
        ps[r] = p; gg[r] = sigm(S2); mg[r] = sigm(S3);
        stv<BF>(out_ps, r, p);
    }
}

// ---------------------------------------------------------------------------
// MFMA GEMM: C[row][col] = sum_k concat(A1,A2)[row][k] * Bm[k][col]
// A: [512,1024]x2 halves (k-contig), 16B vector loads -> bf16 LDS [m][k].
// B: [2048,GN_] row-major; scalar coalesced loads (clamped) -> bf16 LDS [n][k]
//    transposed, b128 writes. BKp=40 keeps ds_read_b128 aligned.
// Pipeline: depth-1 register prefetch — loads for step s+1 issued after the
// LDS store of step s, so their vmcnt drain lands a full compute phase later.
// BIG: grid is (4 M, 393 N) with M fastest so the 4 blocks sharing a B-stripe
// are dispatch-adjacent (co-resident) -> B re-reads hit L2/LLC.
// BIG: out = (acc+bias)*(1-ps[row]).  !BIG: K-split z, f32 atomicAdd epilogue.
// ---------------------------------------------------------------------------
template<int GN_, bool BIG, bool BF>
__global__ __launch_bounds__(256)
void k_gemm(const int* __restrict__ flag,
            const void* __restrict__ A1, const void* __restrict__ A2,
            const void* __restrict__ Bm, const void* __restrict__ bias,
            const float* __restrict__ ps, float* __restrict__ outf,
            void* __restrict__ outh)
{
    if (*flag != (BF ? 1 : 0)) return;
    constexpr int BM = 128, BN = 128, BK = 32, BKp = 40;
    __shared__ ushort_t As[BM*BK];   // 8 KB  [m][k]
    __shared__ ushort_t Bs[BN*BKp];  // 10 KB [n][k]+pad
    const int t = threadIdx.x;
    const int w = t >> 6, l = t & 63;
    const int lr = l & 15, lq = l >> 4;
    // BIG: blockIdx.x = M-block (4), blockIdx.y = N-block; !BIG: original.
    const int nb = BIG ? blockIdx.y : blockIdx.x;
    const int mb = BIG ? blockIdx.x : blockIdx.y;
    const int bn0 = nb * BN;
    const int bm0 = mb * BM;
    const int wm = (w >> 1) * 64, wn = (w & 1) * 64;

    const int steps = BIG ? (GK/BK) : (GK/BK/4);
    const int kbeg  = BIG ? 0 : blockIdx.z * steps * BK;

    const int hB = t >> 7;        // 0/1 : k half for B staging
    const int nB = t & 127;       // n column owned for B staging
    const int gnB = bn0 + nB;
    const size_t gnClamp = (size_t)((gnB < GN_) ? gnB : (GN_-1));
    const bool gnOk = (gnB < GN_);

    f32x4 acc[4][4] = {};
    const ushort_t* a_rd = As + (wm + lr)*BK  + lq*8;
    const ushort_t* b_rd = Bs + (wn + lr)*BKp + lq*8;

    ushort8v aBufH[2]; f32x4v aBufF[4]; float bv[16];

    auto load_step = [&](int s) {
        const int k0 = kbeg + s*BK;
        const void* Asrc = (k0 < H_) ? A1 : A2;
        const int kk = k0 & (H_ - 1);
        if constexpr (BF) {
            #pragma unroll
            for (int p = 0; p < 2; ++p) {
                const int slot = p*256 + t, m = slot >> 2, sub = slot & 3;
                aBufH[p] = *(const ushort8v*)((const ushort_t*)Asrc +
                             (size_t)(bm0 + m)*H_ + kk + sub*8);
            }
        } else {
            #pragma unroll
            for (int p = 0; p < 4; ++p) {
                const int slot = p*256 + t, m = slot >> 3, sub = slot & 7;
                aBufF[p] = *(const f32x4v*)((const float*)Asrc +
                             (size_t)(bm0 + m)*H_ + kk + sub*4);
            }
        }
        #pragma unroll
        for (int p = 0; p < 16; ++p) {
            const int k = hB*16 + p;
            const float v = ldv<BF>(Bm, (size_t)(k0 + k)*GN_ + gnClamp);
            bv[p] = gnOk ? v : 0.f;
        }
    };

    auto store_step = [&]() {
        if constexpr (BF) {
            #pragma unroll
            for (int p = 0; p < 2; ++p) {
                const int slot = p*256 + t, m = slot >> 2, sub = slot & 3;
                *(ushort8v*)(As + m*BK + sub*8) = aBufH[p];
            }
        } else {
            #pragma unroll
            for (int p = 0; p < 4; ++p) {
                const int slot = p*256 + t, m = slot >> 3, sub = slot & 7;
                ushort4v h4;
                h4[0] = f2bf(aBufF[p][0]); h4[1] = f2bf(aBufF[p][1]);
                h4[2] = f2bf(aBufF[p][2]); h4[3] = f2bf(aBufF[p][3]);
                *(ushort4v*)(As + m*BK + sub*4) = h4;
            }
        }
        ushort8v b0, b1;
        #pragma unroll
        for (int p = 0; p < 8; ++p)  b0[p] = f2bf(bv[p]);
        #pragma unroll
        for (int p = 0; p < 8; ++p)  b1[p] = f2bf(bv[8+p]);
        *(ushort8v*)(Bs + nB*BKp + hB*16)     = b0;
        *(ushort8v*)(Bs + nB*BKp + hB*16 + 8) = b1;
    };

    load_step(0);
    for (int s = 0; s < steps; ++s) {
        __syncthreads();   // previous iteration's LDS reads complete
        store_step();
        __syncthreads();   // tile visible to all waves
        if (s + 1 < steps) load_step(s + 1);   // prefetch: drains at next store

        // ---- compute: 4x4 grid of 16x16x32 MFMA per wave ----
        bf16x8 af[4], bfr[4];
        #pragma unroll
        for (int i = 0; i < 4; ++i) af[i]  = *(const bf16x8*)(a_rd + i*16*BK);
        #pragma unroll
        for (int j = 0; j < 4; ++j) bfr[j] = *(const bf16x8*)(b_rd + j*16*BKp);
        #pragma unroll
        for (int i = 0; i < 4; ++i)
            #pragma unroll
            for (int j = 0; j < 4; ++j)
                acc[i][j] = __builtin_amdgcn_mfma_f32_16x16x32_bf16(af[i], bfr[j], acc[i][j], 0, 0, 0);
    }

    // ---- epilogue (C/D: col=lane&15, row=(lane>>4)*4+reg) ----
    if constexpr (BIG) {
        float omp[16];
        #pragma unroll
        for (int i = 0; i < 4; ++i)
            #pragma unroll
            for (int r2 = 0; r2 < 4; ++r2)
                omp[i*4 + r2] = 1.0f - ps[bm0 + wm + i*16 + lq*4 + r2];
        #pragma unroll
        for (int j = 0; j < 4; ++j) {
            const int gcol = bn0 + wn + j*16 + lr;
            if (gcol < GN_) {
                const float bvv = ldv<BF>(bias, gcol);
                #pragma unroll
                for (int i = 0; i < 4; ++i)
                    #pragma unroll
                    for (int r2 = 0; r2 < 4; ++r2) {
                        const int row = bm0 + wm + i*16 + lq*4 + r2;
                        stv<BF>(outh, (size_t)row*GN_ + gcol,
                                (acc[i][j][r2] + bvv) * omp[i*4 + r2]);
                    }
            }
        }
    } else {
        #pragma unroll
        for (int j = 0; j < 4; ++j) {
            const int gcol = bn0 + wn + j*16 + lr;
            if (gcol < GN_) {
                const float bvv = (blockIdx.z == 0) ? ldv<BF>(bias, gcol) : 0.0f;
                #pragma unroll
                for (int i = 0; i < 4; ++i)
                    #pragma unroll
                    for (int r2 = 0; r2 < 4; ++r2) {
                        const int row = bm0 + wm + i*16 + lq*4 + r2;
                        atomicAdd(outf + (size_t)row*GN_ + gcol, acc[i][j][r2] + bvv);
                    }
            }
        }
    }
}

// ---------------------------------------------------------------------------
__global__ void k_graph(const int* __restrict__ edges, float* __restrict__ Graph)
{
    const int gid = blockIdx.x * 256 + threadIdx.x;
    if (gid >= B_*E_) return;
    const int b = gid / E_, e = gid - b*E_;
    const int* eb = edges + (size_t)b * 2 * E_;
    const int i = eb[e], j = eb[E_ + e];
    atomicAdd(Graph + (size_t)b*N_*N_ + (size_t)j*N_ + i, 1.0f);   // Graph^T
}

__global__ void k_scan(const float* __restrict__ cp, const float* __restrict__ mg,
                       float* __restrict__ M)
{
    const int gid = blockIdx.x * 256 + threadIdx.x;
    if (gid >= B_*N_) return;
    const int b = gid / N_, n = gid - b*N_;
    float m = 0.f;
    for (int tt = 0; tt < T_; ++tt) {
        const int r = b*T_ + tt;
        const float g = mg[r];
        m = cp[(size_t)r*N_ + n]*g + m*(1.f - g);
        M[(size_t)r*N_ + n] = m;
    }
}

__global__ __launch_bounds__(320)
void k_gsem(const float* __restrict__ Graph, const float* __restrict__ M,
            const float* __restrict__ cp, const float* __restrict__ gg,
            const float* __restrict__ ps, float* __restrict__ z,
            float* __restrict__ cov)
{
    const int r = blockIdx.x;
    const int b = r >> 7;
    const int t = threadIdx.x, w = t >> 6, l = t & 63;
    __shared__ float ml[N_];
    __shared__ float red[5];
    if (t < N_) ml[t] = M[(size_t)r*N_ + t];
    __syncthreads();
    float g = 0.f;
    if (t < N_) {
        const float* GT = Graph + (size_t)b*N_*N_ + t;
        #pragma unroll 4
        for (int j = 0; j < N_; ++j) g += GT[j*N_] * ml[j];
    }
    float zv = 0.f;
    if (t < N_) {
        const float ggv = gg[r];
        const float pg = cp[(size_t)r*N_ + t]*ggv + g*(1.f - ggv);
        zv = pg * ps[r];
        z[(size_t)r*N_ + t] = zv;
    }
    float mv = (t < N_) ? zv : -3.0e38f;
    for (int o = 32; o; o >>= 1) mv = fmaxf(mv, __shfl_down(mv, o));
    if (l == 0) red[w] = mv;
    __syncthreads();
    const float bmx = fmaxf(fmaxf(fmaxf(red[0], red[1]), fmaxf(red[2], red[3])), red[4]);
    __syncthreads();
    const float e = (t < N_) ? expf(zv - bmx) : 0.f;
    float sv = e;
    for (int o = 32; o; o >>= 1) sv += __shfl_down(sv, o);
    if (l == 0) red[w] = sv;
    __syncthreads();
    const float tot = red[0] + red[1] + red[2] + red[3] + red[4];
    if (t < N_) atomicAdd(cov + b*N_ + t, e / tot);
}

template<bool BF>
__global__ void k_cov(const int* __restrict__ flag,
                      const float* __restrict__ cov, void* __restrict__ out)
{
    if (*flag != (BF ? 1 : 0)) return;
    const int gid = blockIdx.x * 256 + threadIdx.x;
    if (gid < B_*N_) stv<BF>(out, gid, cov[gid]);
}

// out[r, idx[n]] += sum of duplicates' z (first-occurrence thread owns column)
template<bool BF>
__global__ __launch_bounds__(256)
void k_fixup(const int* __restrict__ flag, const int* __restrict__ nidx,
             const float* __restrict__ z, void* __restrict__ out)
{
    if (*flag != (BF ? 1 : 0)) return;
    __shared__ int li[N_];
    const int t = threadIdx.x;
    for (int i = t; i < N_; i += 256) li[i] = nidx[i];
    __syncthreads();
    const int gid = blockIdx.x * 256 + t;
    if (gid >= R_*N_) return;
    const int r = gid / N_, n = gid - r*N_;
    const int v = li[n];
    for (int j = 0; j < n; ++j) if (li[j] == v) return;
    float s = z[(size_t)r*N_ + n];
    for (int j = n + 1; j < N_; ++j) if (li[j] == v) s += z[(size_t)r*N_ + j];
    const size_t o = (size_t)r*V_ + v;
    stv<BF>(out, o, ldv<BF>(out, o) + s);
}

// ---------------------------------------------------------------------------
extern "C" void kernel_launch(void* const* d_in, const int* in_sizes, int n_in,
                              void* d_out, int out_size, void* d_ws, size_t ws_size,
                              hipStream_t stream)
{
    (void)in_sizes; (void)n_in; (void)out_size; (void)ws_size;
    const void* hs  = d_in[0];
    const void* qt  = d_in[1];
    const void* te  = d_in[2];
    const int*  edg = (const int*)d_in[3];
    const int*  nid = (const int*)d_in[4];
    const void* Wg  = d_in[5];
    const void* bg  = d_in[6];
    const void* Wh  = d_in[7];
    const void* Wsm = d_in[8];
    const void* Wx  = d_in[9];
    const void* bx  = d_in[10];
    const void* Wps = d_in[11];
    const void* bps = d_in[12];
    const void* Wc  = d_in[13];
    const void* bc  = d_in[14];
    const void* Wgg = d_in[15];
    const void* bgg = d_in[16];
    const void* Wmg = d_in[17];
    const void* bmg = d_in[18];
    float* ws = (float*)d_ws;
    int* flag = (int*)(ws + FLAG_OFF);

    k_probe<<<1, 64, 0, stream>>>((const ushort_t*)hs, flag);
    hipMemsetAsync(ws + CP_OFF, 0,
                   (size_t)(R_*N_ + B_*N_*N_ + B_*N_) * sizeof(float), stream);

    k_u<true ><<<769, 256, 0, stream>>>(flag, Wh, Wsm, Wx, bx, Wps, bps, ws + U_OFF);
    k_u<false><<<769, 256, 0, stream>>>(flag, Wh, Wsm, Wx, bx, Wps, bps, ws + U_OFF);
    k_rows<true ><<<R_, 256, 0, stream>>>(flag, hs, qt, te, ws + U_OFF, Wgg, bgg, Wmg, bmg,
                                          ws + PS_OFF, ws + GG_OFF, ws + MG_OFF,
                                          (ushort_t*)d_out + OUT_PS);   // elem offset same both dtypes
    k_rows<false><<<R_, 256, 0, stream>>>(flag, hs, qt, te, ws + U_OFF, Wgg, bgg, Wmg, bmg,
                                          ws + PS_OFF, ws + GG_OFF, ws + MG_OFF,
                                          (float*)d_out + OUT_PS);
    {   // copy_pro = concat(qt,te) @ Wc + bc  (K-split x4, f32 atomic epilogue)
        dim3 g((N_ + 127) / 128, 4, 4);
        k_gemm<N_, false, true ><<<g, 256, 0, stream>>>(flag, qt, te, Wc, bc, nullptr,
                                                        ws + CP_OFF, nullptr);
        k_gemm<N_, false, false><<<g, 256, 0, stream>>>(flag, qt, te, Wc, bc, nullptr,
                                                        ws + CP_OFF, nullptr);
    }
    k_graph<<<(B_*E_ + 255)/256, 256, 0, stream>>>(edg, ws + GRAPH_OFF);
    k_scan<<<(B_*N_ + 255)/256, 256, 0, stream>>>(ws + CP_OFF, ws + MG_OFF, ws + M_OFF);
    k_gsem<<<R_, 320, 0, stream>>>(ws + GRAPH_OFF, ws + M_OFF, ws + CP_OFF,
                                   ws + GG_OFF, ws + PS_OFF, ws + Z_OFF, ws + COV_OFF);
    k_cov<true ><<<(B_*N_ + 255)/256, 256, 0, stream>>>(flag, ws + COV_OFF,
                                                        (ushort_t*)d_out + OUT_COV);
    k_cov<false><<<(B_*N_ + 255)/256, 256, 0, stream>>>(flag, ws + COV_OFF,
                                                        (float*)d_out + OUT_COV);
    {   // total_pro = (hq @ Wg + bg) * (1 - ps)
        // M-major grid: 4 same-N blocks dispatch-adjacent for B-stripe L2/LLC reuse
        dim3 g(4, (V_ + 127) / 128, 1);
        k_gemm<V_, true, true ><<<g, 256, 0, stream>>>(flag, hs, qt, Wg, bg, ws + PS_OFF,
                                                       nullptr, d_out);
        k_gemm<V_, true, false><<<g, 256, 0, stream>>>(flag, hs, qt, Wg, bg, ws + PS_OFF,
                                                       nullptr, d_out);
    }
    k_fixup<true ><<<(R_*N_ + 255)/256, 256, 0, stream>>>(flag, nid, ws + Z_OFF, d_out);
    k_fixup<false><<<(R_*N_ + 255)/256, 256, 0, stream>>>(flag, nid, ws + Z_OFF, d_out);
}